// Round 1
// baseline (1317.644 us; speedup 1.0000x reference)
//
#include <hip/hip_runtime.h>
#include <math.h>

#define N_NODES 100000
#define N_EDGES 3200000
#define D_IN 512
#define D_OUT 256
#define NB_SCAN 98   // ceil(100000/1024)

typedef unsigned short ushort_t;
typedef unsigned int uint_t;

using f32x4 = __attribute__((ext_vector_type(4))) float;
using s16x8 = __attribute__((ext_vector_type(8))) short;
using s16x4 = __attribute__((ext_vector_type(4))) short;

__device__ __forceinline__ ushort_t f2bf(float f) {
    union { float f; uint_t u; } v; v.f = f;
    uint_t r = v.u + 0x7FFFu + ((v.u >> 16) & 1u);   // round-to-nearest-even
    return (ushort_t)(r >> 16);
}
__device__ __forceinline__ float bf2f(ushort_t u) {
    union { uint_t u; float f; } v; v.u = ((uint_t)u) << 16;
    return v.f;
}

// ---------------------------------------------------------------------------
// Kernel 1: pre_sup = x @ W  (fp32 in, bf16 MFMA, bf16 out)
// Block tile 128(M) x 128(N), BK=32, 4 waves of 64x64, 16x16x32 bf16 MFMA.
// blockIdx.x = n-tile (2, fast-varying for x-reuse in L2/L3), blockIdx.y = m-tile (782)
// ---------------------------------------------------------------------------
__global__ __launch_bounds__(256) void gemm_xw(const float* __restrict__ X,
                                               const float* __restrict__ W,
                                               ushort_t* __restrict__ P) {
    __shared__ ushort_t As[128 * 32];   // [m][k], 8 KB
    __shared__ ushort_t Bs[128 * 32];   // [n][k] (transposed), 8 KB
    const int tid = threadIdx.x;
    const int n0 = blockIdx.x * 128;
    const int m0 = blockIdx.y * 128;
    const int wave = tid >> 6, lane = tid & 63;
    const int quad = lane >> 4, r16 = lane & 15;
    const int wm = (wave >> 1) * 64, wn = (wave & 1) * 64;

    f32x4 acc[4][4] = {};

    for (int k0 = 0; k0 < D_IN; k0 += 32) {
        // stage A: 128x32 fp32 -> bf16, row-major [m][k]
#pragma unroll
        for (int i = 0; i < 4; ++i) {
            int f = tid + i * 256;            // f < 1024 float4s
            int row = f >> 3, c4 = (f & 7) * 4;
            int grow = m0 + row;
            f32x4 v = {0.f, 0.f, 0.f, 0.f};
            if (grow < N_NODES)
                v = *(const f32x4*)(X + (size_t)grow * D_IN + k0 + c4);
            s16x4 bv;
            bv.x = (short)f2bf(v.x); bv.y = (short)f2bf(v.y);
            bv.z = (short)f2bf(v.z); bv.w = (short)f2bf(v.w);
            *(s16x4*)(&As[row * 32 + c4]) = bv;
        }
        // stage B: W[k0..k0+32][n0..n0+128] -> Bs[n][k] transposed bf16
#pragma unroll
        for (int i = 0; i < 4; ++i) {
            int f = tid + i * 256;
            int krow = f >> 5, c4 = (f & 31) * 4;
            f32x4 v = *(const f32x4*)(W + (size_t)(k0 + krow) * D_OUT + n0 + c4);
            Bs[(c4 + 0) * 32 + krow] = f2bf(v.x);
            Bs[(c4 + 1) * 32 + krow] = f2bf(v.y);
            Bs[(c4 + 2) * 32 + krow] = f2bf(v.z);
            Bs[(c4 + 3) * 32 + krow] = f2bf(v.w);
        }
        __syncthreads();

        s16x8 a[4], b[4];
#pragma unroll
        for (int i = 0; i < 4; ++i)
            a[i] = *(const s16x8*)(&As[(wm + i * 16 + r16) * 32 + quad * 8]);
#pragma unroll
        for (int j = 0; j < 4; ++j)
            b[j] = *(const s16x8*)(&Bs[(wn + j * 16 + r16) * 32 + quad * 8]);
#pragma unroll
        for (int i = 0; i < 4; ++i)
#pragma unroll
            for (int j = 0; j < 4; ++j)
                acc[i][j] = __builtin_amdgcn_mfma_f32_16x16x32_bf16(a[i], b[j], acc[i][j], 0, 0, 0);
        __syncthreads();
    }

    // epilogue: C/D layout col=lane&15, row=quad*4+reg  [verified m89/m91]
#pragma unroll
    for (int i = 0; i < 4; ++i) {
#pragma unroll
        for (int rr = 0; rr < 4; ++rr) {
            int grow = m0 + wm + i * 16 + quad * 4 + rr;
            if (grow >= N_NODES) continue;
#pragma unroll
            for (int j = 0; j < 4; ++j) {
                int gcol = n0 + wn + j * 16 + r16;
                P[(size_t)grow * D_OUT + gcol] = f2bf(acc[i][j][rr]);
            }
        }
    }
}

// ---------------------------------------------------------------------------
// CSR build: histogram -> hierarchical exclusive scan -> scatter
// ---------------------------------------------------------------------------
__global__ __launch_bounds__(256) void hist_kernel(const int* __restrict__ erow,
                                                   int* __restrict__ cnt) {
    int e = blockIdx.x * 256 + threadIdx.x;
    if (e < N_EDGES) atomicAdd(&cnt[erow[e]], 1);
}

__global__ __launch_bounds__(256) void scan_block_sums(const int* __restrict__ cnt,
                                                       int* __restrict__ bsum) {
    __shared__ int sdata[256];
    int t = threadIdx.x;
    int base = blockIdx.x * 1024 + t * 4;
    int s = 0;
#pragma unroll
    for (int j = 0; j < 4; ++j) {
        int i = base + j;
        if (i < N_NODES) s += cnt[i];
    }
    sdata[t] = s;
    __syncthreads();
    for (int off = 128; off > 0; off >>= 1) {
        if (t < off) sdata[t] += sdata[t + off];
        __syncthreads();
    }
    if (t == 0) bsum[blockIdx.x] = sdata[0];
}

__global__ void scan_offsets(const int* __restrict__ bsum, int* __restrict__ boff) {
    __shared__ int sdata[128];
    int t = threadIdx.x;
    int v = (t < NB_SCAN) ? bsum[t] : 0;
    sdata[t] = v;
    __syncthreads();
    for (int off = 1; off < 128; off <<= 1) {
        int x = (t >= off) ? sdata[t - off] : 0;
        __syncthreads();
        sdata[t] += x;
        __syncthreads();
    }
    if (t < NB_SCAN) boff[t] = sdata[t] - v;   // exclusive
}

__global__ __launch_bounds__(256) void scan_final(const int* __restrict__ cnt,
                                                  const int* __restrict__ boff,
                                                  int* __restrict__ row_start,
                                                  int* __restrict__ cursor) {
    __shared__ int sdata[256];
    int t = threadIdx.x;
    int base = blockIdx.x * 1024 + t * 4;
    int v[4]; int s = 0;
#pragma unroll
    for (int j = 0; j < 4; ++j) {
        int i = base + j;
        v[j] = (i < N_NODES) ? cnt[i] : 0;
        s += v[j];
    }
    sdata[t] = s;
    __syncthreads();
    for (int off = 1; off < 256; off <<= 1) {
        int x = (t >= off) ? sdata[t - off] : 0;
        __syncthreads();
        sdata[t] += x;
        __syncthreads();
    }
    int run = boff[blockIdx.x] + sdata[t] - s;   // global exclusive prefix
#pragma unroll
    for (int j = 0; j < 4; ++j) {
        int i = base + j;
        if (i < N_NODES) { row_start[i] = run; cursor[i] = run; run += v[j]; }
    }
    if (blockIdx.x == 0 && t == 0) row_start[N_NODES] = N_EDGES;
}

__global__ __launch_bounds__(256) void scatter_edges(const int* __restrict__ erow,
                                                     const int* __restrict__ ecol,
                                                     const float* __restrict__ eval,
                                                     int* __restrict__ cursor,
                                                     uint2* __restrict__ csr) {
    int e = blockIdx.x * 256 + threadIdx.x;
    if (e < N_EDGES) {
        int r = erow[e];
        int pos = atomicAdd(&cursor[r], 1);
        uint2 p; p.x = (uint_t)ecol[e]; p.y = __float_as_uint(eval[e]);
        csr[pos] = p;
    }
}

// ---------------------------------------------------------------------------
// SpMM row-gather: one block per node, thread = feature. Writes agg+b to out.
// ---------------------------------------------------------------------------
__global__ __launch_bounds__(256) void spmm_kernel(const uint2* __restrict__ csr,
                                                   const int* __restrict__ row_start,
                                                   const ushort_t* __restrict__ pre,
                                                   const float* __restrict__ bias,
                                                   float* __restrict__ out) {
    __shared__ uint2 epairs[256];
    const int node = blockIdx.x;
    const int f = threadIdx.x;
    const int beg = row_start[node], end = row_start[node + 1];
    float acc = 0.f;
    for (int base = beg; base < end; base += 256) {
        int cnt = min(end - base, 256);
        if (f < cnt) epairs[f] = csr[base + f];
        __syncthreads();
        int e = 0;
        for (; e + 4 <= cnt; e += 4) {
            uint2 p0 = epairs[e], p1 = epairs[e + 1], p2 = epairs[e + 2], p3 = epairs[e + 3];
            float g0 = bf2f(pre[(size_t)p0.x * D_OUT + f]);
            float g1 = bf2f(pre[(size_t)p1.x * D_OUT + f]);
            float g2 = bf2f(pre[(size_t)p2.x * D_OUT + f]);
            float g3 = bf2f(pre[(size_t)p3.x * D_OUT + f]);
            acc = fmaf(__uint_as_float(p0.y), g0, acc);
            acc = fmaf(__uint_as_float(p1.y), g1, acc);
            acc = fmaf(__uint_as_float(p2.y), g2, acc);
            acc = fmaf(__uint_as_float(p3.y), g3, acc);
        }
        for (; e < cnt; ++e) {
            uint2 p = epairs[e];
            acc = fmaf(__uint_as_float(p.y), bf2f(pre[(size_t)p.x * D_OUT + f]), acc);
        }
        __syncthreads();
    }
    out[(size_t)node * D_OUT + f] = acc + bias[f];
}

// ---------------------------------------------------------------------------
// Column sum-of-squares (over node dim), then in-place normalize + softplus
// ---------------------------------------------------------------------------
__global__ __launch_bounds__(256) void colsq_kernel(const float* __restrict__ out,
                                                    float* __restrict__ colsq) {
    const int f = threadIdx.x;
    float s = 0.f;
    for (int i = blockIdx.x; i < N_NODES; i += gridDim.x) {
        float v = out[(size_t)i * D_OUT + f];
        s = fmaf(v, v, s);
    }
    atomicAdd(&colsq[f], s);
}

__global__ __launch_bounds__(256) void finalize_kernel(float* __restrict__ out,
                                                       const float* __restrict__ colsq) {
    __shared__ float inv[256];
    const int t = threadIdx.x;
    float n = sqrtf(colsq[t]);
    inv[t] = 1.0f / fmaxf(n, 1e-12f);
    __syncthreads();
    const size_t total4 = (size_t)N_NODES * D_OUT / 4;
    for (size_t i = (size_t)blockIdx.x * 256 + t; i < total4; i += (size_t)gridDim.x * 256) {
        f32x4 v = ((const f32x4*)out)[i];
        int fbase = (int)((i * 4) & (D_OUT - 1));
        f32x4 o;
#pragma unroll
        for (int c = 0; c < 4; ++c) {
            float x = v[c] * inv[fbase + c];
            o[c] = (x > 20.f) ? x : log1pf(expf(x));
        }
        ((f32x4*)out)[i] = o;
    }
}

// ---------------------------------------------------------------------------
extern "C" void kernel_launch(void* const* d_in, const int* in_sizes, int n_in,
                              void* d_out, int out_size, void* d_ws, size_t ws_size,
                              hipStream_t stream) {
    const float* x    = (const float*)d_in[0];
    const int*   erow = (const int*)d_in[1];
    const int*   ecol = (const int*)d_in[2];
    const float* eval = (const float*)d_in[3];
    const float* W    = (const float*)d_in[4];
    const float* b    = (const float*)d_in[5];
    float* out = (float*)d_out;
    char* ws = (char*)d_ws;

    // workspace layout (~78 MB)
    ushort_t* pre    = (ushort_t*)(ws + 0);            // 51,200,000 B
    uint2*    csr    = (uint2*)   (ws + 51200000);     // 25,600,000 B (8B aligned)
    int*      cnt    = (int*)     (ws + 76800000);     //    400,000 B
    int*      rstart = (int*)     (ws + 77200000);     //    400,004 B
    int*      cursor = (int*)     (ws + 77600016);     //    400,000 B
    float*    colsq  = (float*)   (ws + 78000016);     //      1,024 B
    int*      bsum   = (int*)     (ws + 78001040);     //        392 B
    int*      boff   = (int*)     (ws + 78001552);     //        392 B

    (void)hipMemsetAsync(cnt, 0, N_NODES * sizeof(int), stream);
    (void)hipMemsetAsync(colsq, 0, D_OUT * sizeof(float), stream);

    gemm_xw<<<dim3(2, 782), 256, 0, stream>>>(x, W, pre);
    hist_kernel<<<N_EDGES / 256, 256, 0, stream>>>(erow, cnt);
    scan_block_sums<<<NB_SCAN, 256, 0, stream>>>(cnt, bsum);
    scan_offsets<<<1, 128, 0, stream>>>(bsum, boff);
    scan_final<<<NB_SCAN, 256, 0, stream>>>(cnt, boff, rstart, cursor);
    scatter_edges<<<N_EDGES / 256, 256, 0, stream>>>(erow, ecol, eval, cursor, csr);
    spmm_kernel<<<N_NODES, 256, 0, stream>>>(csr, rstart, pre, b, out);
    colsq_kernel<<<512, 256, 0, stream>>>(out, colsq);
    finalize_kernel<<<1024, 256, 0, stream>>>(out, colsq);
}

// Round 3
// 1070.987 us; speedup vs baseline: 1.2303x; 1.2303x over previous
//
#include <hip/hip_runtime.h>
#include <math.h>

#define N_NODES 100000
#define N_EDGES 3200000
#define D_IN 512
#define D_OUT 256
#define NB_SCAN 98   // ceil(100000/1024)
#define LDA 40       // padded LDS row stride (ushorts): 80 B, breaks pow-2 bank aliasing

typedef unsigned short ushort_t;
typedef unsigned int uint_t;

using f32x4 = __attribute__((ext_vector_type(4))) float;
using s16x8 = __attribute__((ext_vector_type(8))) short;

__device__ __forceinline__ ushort_t f2bf(float f) {
    union { float f; uint_t u; } v; v.f = f;
    uint_t r = v.u + 0x7FFFu + ((v.u >> 16) & 1u);   // round-to-nearest-even
    return (ushort_t)(r >> 16);
}
__device__ __forceinline__ float bf2f(uint_t u) {   // low 16 bits = bf16
    union { uint_t u; float f; } v; v.u = u << 16;
    return v.f;
}

// ---------------------------------------------------------------------------
// W [512][256] fp32 -> Wt [256][512] bf16 (transposed so GEMM B-staging is
// contiguous-in-k vectorized copies)
// ---------------------------------------------------------------------------
__global__ __launch_bounds__(256) void cvt_w(const float* __restrict__ W,
                                             ushort_t* __restrict__ Wt) {
    int idx = blockIdx.x * 256 + threadIdx.x;   // 131072 total
    int k = idx >> 8, n = idx & 255;
    Wt[(size_t)n * D_IN + k] = f2bf(W[idx]);
}

// ---------------------------------------------------------------------------
// pre_sup = x @ W  (fp32 in, bf16 MFMA, bf16 out)
// 128x128 block tile, BK=32, 4 waves of 64x64, 16x16x32 bf16 MFMA.
// LDS rows padded to 40 ushorts -> <=2-way bank aliasing (free) on both the
// ds_write_b128 staging and the ds_read_b128 fragment loads.
// ---------------------------------------------------------------------------
__global__ __launch_bounds__(256) void gemm_xw(const float* __restrict__ X,
                                               const ushort_t* __restrict__ Wt,
                                               ushort_t* __restrict__ P) {
    __shared__ ushort_t As[128 * LDA];   // 10240 B
    __shared__ ushort_t Bs[128 * LDA];   // 10240 B
    const int tid = threadIdx.x;
    const int n0 = blockIdx.x * 128;
    const int m0 = blockIdx.y * 128;
    const int wave = tid >> 6, lane = tid & 63;
    const int quad = lane >> 4, r16 = lane & 15;
    const int wm = (wave >> 1) * 64, wn = (wave & 1) * 64;

    f32x4 acc[4][4] = {};

    for (int k0 = 0; k0 < D_IN; k0 += 32) {
        // stage A (X fp32 -> bf16) and B (Wt bf16 copy): 512 16B-chunks each,
        // 2 chunks per thread. chunk f: row=f>>2, kc=(f&3)*8
#pragma unroll
        for (int it = 0; it < 2; ++it) {
            int f = tid + it * 256;
            int row = f >> 2, kc = (f & 3) * 8;
            int grow = m0 + row;
            s16x8 av = {};
            if (grow < N_NODES) {
                const float* xp = X + (size_t)grow * D_IN + k0 + kc;
                f32x4 v0 = *(const f32x4*)(xp);
                f32x4 v1 = *(const f32x4*)(xp + 4);
                av[0] = (short)f2bf(v0[0]); av[1] = (short)f2bf(v0[1]);
                av[2] = (short)f2bf(v0[2]); av[3] = (short)f2bf(v0[3]);
                av[4] = (short)f2bf(v1[0]); av[5] = (short)f2bf(v1[1]);
                av[6] = (short)f2bf(v1[2]); av[7] = (short)f2bf(v1[3]);
            }
            *(s16x8*)(&As[row * LDA + kc]) = av;
            s16x8 bv = *(const s16x8*)(Wt + (size_t)(n0 + row) * D_IN + k0 + kc);
            *(s16x8*)(&Bs[row * LDA + kc]) = bv;
        }
        __syncthreads();

        s16x8 a[4], b[4];
#pragma unroll
        for (int i = 0; i < 4; ++i)
            a[i] = *(const s16x8*)(&As[(wm + i * 16 + r16) * LDA + quad * 8]);
#pragma unroll
        for (int j = 0; j < 4; ++j)
            b[j] = *(const s16x8*)(&Bs[(wn + j * 16 + r16) * LDA + quad * 8]);
#pragma unroll
        for (int i = 0; i < 4; ++i)
#pragma unroll
            for (int j = 0; j < 4; ++j)
                acc[i][j] = __builtin_amdgcn_mfma_f32_16x16x32_bf16(a[i], b[j], acc[i][j], 0, 0, 0);
        __syncthreads();
    }

    // epilogue: C/D layout col=lane&15, row=quad*4+reg (empirically verified R1)
#pragma unroll
    for (int i = 0; i < 4; ++i) {
#pragma unroll
        for (int rr = 0; rr < 4; ++rr) {
            int grow = m0 + wm + i * 16 + quad * 4 + rr;
            if (grow >= N_NODES) continue;
#pragma unroll
            for (int j = 0; j < 4; ++j) {
                int gcol = n0 + wn + j * 16 + r16;
                P[(size_t)grow * D_OUT + gcol] = f2bf(acc[i][j][rr]);
            }
        }
    }
}

// ---------------------------------------------------------------------------
// CSR build: histogram -> hierarchical exclusive scan -> scatter
// ---------------------------------------------------------------------------
__global__ __launch_bounds__(256) void hist_kernel(const int* __restrict__ erow,
                                                   int* __restrict__ cnt) {
    int e = blockIdx.x * 256 + threadIdx.x;
    if (e < N_EDGES) atomicAdd(&cnt[erow[e]], 1);
}

__global__ __launch_bounds__(256) void scan_block_sums(const int* __restrict__ cnt,
                                                       int* __restrict__ bsum) {
    __shared__ int sdata[256];
    int t = threadIdx.x;
    int base = blockIdx.x * 1024 + t * 4;
    int s = 0;
#pragma unroll
    for (int j = 0; j < 4; ++j) {
        int i = base + j;
        if (i < N_NODES) s += cnt[i];
    }
    sdata[t] = s;
    __syncthreads();
    for (int off = 128; off > 0; off >>= 1) {
        if (t < off) sdata[t] += sdata[t + off];
        __syncthreads();
    }
    if (t == 0) bsum[blockIdx.x] = sdata[0];
}

__global__ void scan_offsets(const int* __restrict__ bsum, int* __restrict__ boff) {
    __shared__ int sdata[128];
    int t = threadIdx.x;
    int v = (t < NB_SCAN) ? bsum[t] : 0;
    sdata[t] = v;
    __syncthreads();
    for (int off = 1; off < 128; off <<= 1) {
        int x = (t >= off) ? sdata[t - off] : 0;
        __syncthreads();
        sdata[t] += x;
        __syncthreads();
    }
    if (t < NB_SCAN) boff[t] = sdata[t] - v;   // exclusive
}

__global__ __launch_bounds__(256) void scan_final(const int* __restrict__ cnt,
                                                  const int* __restrict__ boff,
                                                  int* __restrict__ row_start,
                                                  int* __restrict__ cursor) {
    __shared__ int sdata[256];
    int t = threadIdx.x;
    int base = blockIdx.x * 1024 + t * 4;
    int v[4]; int s = 0;
#pragma unroll
    for (int j = 0; j < 4; ++j) {
        int i = base + j;
        v[j] = (i < N_NODES) ? cnt[i] : 0;
        s += v[j];
    }
    sdata[t] = s;
    __syncthreads();
    for (int off = 1; off < 256; off <<= 1) {
        int x = (t >= off) ? sdata[t - off] : 0;
        __syncthreads();
        sdata[t] += x;
        __syncthreads();
    }
    int run = boff[blockIdx.x] + sdata[t] - s;   // global exclusive prefix
#pragma unroll
    for (int j = 0; j < 4; ++j) {
        int i = base + j;
        if (i < N_NODES) { row_start[i] = run; cursor[i] = run; run += v[j]; }
    }
    if (blockIdx.x == 0 && t == 0) row_start[N_NODES] = N_EDGES;
}

__global__ __launch_bounds__(256) void scatter_edges(const int* __restrict__ erow,
                                                     const int* __restrict__ ecol,
                                                     const float* __restrict__ eval,
                                                     int* __restrict__ cursor,
                                                     uint2* __restrict__ csr) {
    int e = blockIdx.x * 256 + threadIdx.x;
    if (e < N_EDGES) {
        int r = erow[e];
        int pos = atomicAdd(&cursor[r], 1);
        uint2 p; p.x = (uint_t)ecol[e]; p.y = __float_as_uint(eval[e]);
        csr[pos] = p;
    }
}

// ---------------------------------------------------------------------------
// SpMM row-gather: ONE WAVE per node; lane owns 4 features (one dwordx2 per
// edge fetches them) -> whole 512 B pre-row in a single VMEM instr per wave.
// Writes agg + bias into out.
// ---------------------------------------------------------------------------
__global__ __launch_bounds__(64) void spmm_kernel(const uint2* __restrict__ csr,
                                                  const int* __restrict__ row_start,
                                                  const ushort_t* __restrict__ pre,
                                                  const float* __restrict__ bias,
                                                  float* __restrict__ out) {
    __shared__ uint2 epairs[64];
    const int node = blockIdx.x;
    const int lane = threadIdx.x;          // 0..63
    const int beg = row_start[node], end = row_start[node + 1];
    float a0 = 0.f, a1 = 0.f, a2 = 0.f, a3 = 0.f;
    for (int base = beg; base < end; base += 64) {
        int cnt = min(end - base, 64);
        if (lane < cnt) epairs[lane] = csr[base + lane];
        __syncthreads();
        for (int e = 0; e < cnt; ++e) {
            uint2 p = epairs[e];
            float w = __uint_as_float(p.y);
            const uint_t* rowp = (const uint_t*)(pre + (size_t)p.x * D_OUT);
            uint2 g = *(const uint2*)(rowp + lane * 2);   // features lane*4 .. lane*4+3
            a0 = fmaf(w, bf2f(g.x & 0xFFFFu), a0);
            a1 = fmaf(w, bf2f(g.x >> 16), a1);
            a2 = fmaf(w, bf2f(g.y & 0xFFFFu), a2);
            a3 = fmaf(w, bf2f(g.y >> 16), a3);
        }
        __syncthreads();
    }
    const float* b4 = bias + lane * 4;
    f32x4 o;
    o[0] = a0 + b4[0]; o[1] = a1 + b4[1]; o[2] = a2 + b4[2]; o[3] = a3 + b4[3];
    *(f32x4*)(out + (size_t)node * D_OUT + lane * 4) = o;
}

// ---------------------------------------------------------------------------
// Column sum-of-squares (over node dim), then in-place normalize + softplus
// ---------------------------------------------------------------------------
__global__ __launch_bounds__(256) void colsq_kernel(const float* __restrict__ out,
                                                    float* __restrict__ colsq) {
    const int f = threadIdx.x;
    float s = 0.f;
    for (int i = blockIdx.x; i < N_NODES; i += gridDim.x) {
        float v = out[(size_t)i * D_OUT + f];
        s = fmaf(v, v, s);
    }
    atomicAdd(&colsq[f], s);
}

__global__ __launch_bounds__(256) void finalize_kernel(float* __restrict__ out,
                                                       const float* __restrict__ colsq) {
    __shared__ float inv[256];
    const int t = threadIdx.x;
    float n = sqrtf(colsq[t]);
    inv[t] = 1.0f / fmaxf(n, 1e-12f);
    __syncthreads();
    const size_t total4 = (size_t)N_NODES * D_OUT / 4;
    for (size_t i = (size_t)blockIdx.x * 256 + t; i < total4; i += (size_t)gridDim.x * 256) {
        f32x4 v = ((const f32x4*)out)[i];
        int fbase = (int)((i * 4) & (D_OUT - 1));
        f32x4 o;
#pragma unroll
        for (int c = 0; c < 4; ++c) {
            float x = v[c] * inv[fbase + c];
            // softplus via HIP fast intrinsics (v_exp_f32 / v_log_f32)
            float tt = __expf(x);
            float y = __logf(1.0f + tt);
            o[c] = (x > 20.f) ? x : y;
        }
        ((f32x4*)out)[i] = o;
    }
}

// ---------------------------------------------------------------------------
extern "C" void kernel_launch(void* const* d_in, const int* in_sizes, int n_in,
                              void* d_out, int out_size, void* d_ws, size_t ws_size,
                              hipStream_t stream) {
    const float* x    = (const float*)d_in[0];
    const int*   erow = (const int*)d_in[1];
    const int*   ecol = (const int*)d_in[2];
    const float* eval = (const float*)d_in[3];
    const float* W    = (const float*)d_in[4];
    const float* b    = (const float*)d_in[5];
    float* out = (float*)d_out;
    char* ws = (char*)d_ws;

    // workspace layout (~78.3 MB)
    ushort_t* pre    = (ushort_t*)(ws + 0);            // 51,200,000 B
    uint2*    csr    = (uint2*)   (ws + 51200000);     // 25,600,000 B
    int*      cnt    = (int*)     (ws + 76800000);     //    400,000 B
    int*      rstart = (int*)     (ws + 77200000);     //    400,004 B
    int*      cursor = (int*)     (ws + 77600016);     //    400,000 B
    float*    colsq  = (float*)   (ws + 78000016);     //      1,024 B
    int*      bsum   = (int*)     (ws + 78001040);     //        512 B
    int*      boff   = (int*)     (ws + 78001552);     //        512 B
    ushort_t* Wt     = (ushort_t*)(ws + 78002176);     //    262,144 B

    (void)hipMemsetAsync(cnt, 0, N_NODES * sizeof(int), stream);
    (void)hipMemsetAsync(colsq, 0, D_OUT * sizeof(float), stream);

    cvt_w<<<512, 256, 0, stream>>>(W, Wt);
    gemm_xw<<<dim3(2, 782), 256, 0, stream>>>(x, Wt, pre);
    hist_kernel<<<N_EDGES / 256, 256, 0, stream>>>(erow, cnt);
    scan_block_sums<<<NB_SCAN, 256, 0, stream>>>(cnt, bsum);
    scan_offsets<<<1, 128, 0, stream>>>(bsum, boff);
    scan_final<<<NB_SCAN, 256, 0, stream>>>(cnt, boff, rstart, cursor);
    scatter_edges<<<N_EDGES / 256, 256, 0, stream>>>(erow, ecol, eval, cursor, csr);
    spmm_kernel<<<N_NODES, 64, 0, stream>>>(csr, rstart, pre, b, out);
    colsq_kernel<<<512, 256, 0, stream>>>(out, colsq);
    finalize_kernel<<<1024, 256, 0, stream>>>(out, colsq);
}

// Round 4
// 864.455 us; speedup vs baseline: 1.5242x; 1.2389x over previous
//
#include <hip/hip_runtime.h>
#include <math.h>

#define N_NODES 100000
#define N_EDGES 3200000
#define D_IN 512
#define D_OUT 256
#define NBUK 391     // ceil(100000/256) buckets of 256 rows
#define LDA 40       // padded LDS row stride (ushorts): 80 B, breaks pow-2 bank aliasing

typedef unsigned short ushort_t;
typedef unsigned int uint_t;

using f32x4 = __attribute__((ext_vector_type(4))) float;
using s16x8 = __attribute__((ext_vector_type(8))) short;

__device__ __forceinline__ ushort_t f2bf(float f) {
    union { float f; uint_t u; } v; v.f = f;
    uint_t r = v.u + 0x7FFFu + ((v.u >> 16) & 1u);   // round-to-nearest-even
    return (ushort_t)(r >> 16);
}
__device__ __forceinline__ float bf2f(uint_t u) {   // low 16 bits = bf16
    union { uint_t u; float f; } v; v.u = u << 16;
    return v.f;
}

// ---------------------------------------------------------------------------
// W [512][256] fp32 -> Wt [256][512] bf16 (transposed for GEMM B-staging)
// ---------------------------------------------------------------------------
__global__ __launch_bounds__(256) void cvt_w(const float* __restrict__ W,
                                             ushort_t* __restrict__ Wt) {
    int idx = blockIdx.x * 256 + threadIdx.x;   // 131072 total
    int k = idx >> 8, n = idx & 255;
    Wt[(size_t)n * D_IN + k] = f2bf(W[idx]);
}

// ---------------------------------------------------------------------------
// pre_sup = x @ W  (fp32 in, bf16 MFMA, bf16 out). 128x128 tile, BK=32,
// 4 waves of 64x64, 16x16x32 bf16 MFMA, LDS rows padded to 40 ushorts.
// ---------------------------------------------------------------------------
__global__ __launch_bounds__(256) void gemm_xw(const float* __restrict__ X,
                                               const ushort_t* __restrict__ Wt,
                                               ushort_t* __restrict__ P) {
    __shared__ ushort_t As[128 * LDA];
    __shared__ ushort_t Bs[128 * LDA];
    const int tid = threadIdx.x;
    const int n0 = blockIdx.x * 128;
    const int m0 = blockIdx.y * 128;
    const int wave = tid >> 6, lane = tid & 63;
    const int quad = lane >> 4, r16 = lane & 15;
    const int wm = (wave >> 1) * 64, wn = (wave & 1) * 64;

    f32x4 acc[4][4] = {};

    for (int k0 = 0; k0 < D_IN; k0 += 32) {
#pragma unroll
        for (int it = 0; it < 2; ++it) {
            int f = tid + it * 256;
            int row = f >> 2, kc = (f & 3) * 8;
            int grow = m0 + row;
            s16x8 av = {};
            if (grow < N_NODES) {
                const float* xp = X + (size_t)grow * D_IN + k0 + kc;
                f32x4 v0 = *(const f32x4*)(xp);
                f32x4 v1 = *(const f32x4*)(xp + 4);
                av[0] = (short)f2bf(v0[0]); av[1] = (short)f2bf(v0[1]);
                av[2] = (short)f2bf(v0[2]); av[3] = (short)f2bf(v0[3]);
                av[4] = (short)f2bf(v1[0]); av[5] = (short)f2bf(v1[1]);
                av[6] = (short)f2bf(v1[2]); av[7] = (short)f2bf(v1[3]);
            }
            *(s16x8*)(&As[row * LDA + kc]) = av;
            s16x8 bv = *(const s16x8*)(Wt + (size_t)(n0 + row) * D_IN + k0 + kc);
            *(s16x8*)(&Bs[row * LDA + kc]) = bv;
        }
        __syncthreads();

        s16x8 a[4], b[4];
#pragma unroll
        for (int i = 0; i < 4; ++i)
            a[i] = *(const s16x8*)(&As[(wm + i * 16 + r16) * LDA + quad * 8]);
#pragma unroll
        for (int j = 0; j < 4; ++j)
            b[j] = *(const s16x8*)(&Bs[(wn + j * 16 + r16) * LDA + quad * 8]);
#pragma unroll
        for (int i = 0; i < 4; ++i)
#pragma unroll
            for (int j = 0; j < 4; ++j)
                acc[i][j] = __builtin_amdgcn_mfma_f32_16x16x32_bf16(a[i], b[j], acc[i][j], 0, 0, 0);
        __syncthreads();
    }

#pragma unroll
    for (int i = 0; i < 4; ++i) {
#pragma unroll
        for (int rr = 0; rr < 4; ++rr) {
            int grow = m0 + wm + i * 16 + quad * 4 + rr;
            if (grow >= N_NODES) continue;
#pragma unroll
            for (int j = 0; j < 4; ++j) {
                int gcol = n0 + wn + j * 16 + r16;
                P[(size_t)grow * D_OUT + gcol] = f2bf(acc[i][j][rr]);
            }
        }
    }
}

// ---------------------------------------------------------------------------
// CSR build, bucketed (bucket = 256 consecutive rows, b = row>>8)
// ---------------------------------------------------------------------------
__global__ __launch_bounds__(256) void bhist(const int* __restrict__ erow,
                                             int* __restrict__ bcnt) {
    __shared__ int l[NBUK];
    for (int b = threadIdx.x; b < NBUK; b += 256) l[b] = 0;
    __syncthreads();
    int base = blockIdx.x * 4096;
#pragma unroll
    for (int i = 0; i < 16; ++i) {
        int e = base + i * 256 + threadIdx.x;
        if (e < N_EDGES) atomicAdd(&l[erow[e] >> 8], 1);
    }
    __syncthreads();
    for (int b = threadIdx.x; b < NBUK; b += 256)
        if (l[b]) atomicAdd(&bcnt[b], l[b]);
}

__global__ void bscan(const int* __restrict__ bcnt, int* __restrict__ bbase,
                      int* __restrict__ bcursor, int* __restrict__ rstart) {
    __shared__ int sc[512];
    int t = threadIdx.x;
    int v = (t < NBUK) ? bcnt[t] : 0;
    sc[t] = v;
    __syncthreads();
    for (int off = 1; off < 512; off <<= 1) {
        int x = (t >= off) ? sc[t - off] : 0;
        __syncthreads();
        sc[t] += x;
        __syncthreads();
    }
    if (t < NBUK) { int excl = sc[t] - v; bbase[t] = excl; bcursor[t] = excl; }
    if (t == 0) { bbase[NBUK] = N_EDGES; rstart[N_NODES] = N_EDGES; }
}

// per-block LDS hist -> contiguous range reservation -> run-wise writes
__global__ __launch_bounds__(256) void bucket_scatter(const int* __restrict__ erow,
                                                      const int* __restrict__ ecol,
                                                      const float* __restrict__ eval,
                                                      int* __restrict__ bcursor,
                                                      uint2* __restrict__ bkt) {
    __shared__ int lcnt[NBUK];
    __shared__ int lbase[NBUK];
    const int t = threadIdx.x;
    for (int b = t; b < NBUK; b += 256) lcnt[b] = 0;
    __syncthreads();
    const int base = blockIdx.x * 4096;
#pragma unroll
    for (int i = 0; i < 16; ++i) {
        int e = base + i * 256 + t;
        if (e < N_EDGES) atomicAdd(&lcnt[erow[e] >> 8], 1);
    }
    __syncthreads();
    for (int b = t; b < NBUK; b += 256) {
        int c = lcnt[b];
        if (c) lbase[b] = atomicAdd(&bcursor[b], c);
        lcnt[b] = 0;
    }
    __syncthreads();
#pragma unroll
    for (int i = 0; i < 16; ++i) {
        int e = base + i * 256 + t;
        if (e < N_EDGES) {
            int r = erow[e];
            int b = r >> 8;
            int off = atomicAdd(&lcnt[b], 1);
            uint2 p;
            p.x = ((uint_t)(r & 255) << 17) | (uint_t)ecol[e];   // lrow(8b)|col(17b)
            p.y = __float_as_uint(eval[e]);
            bkt[lbase[b] + off] = p;
        }
    }
}

// one block per bucket: LDS row-hist + scan (produces row_start), then
// scatter into this bucket's ~65 KB csr window (single block => one XCD)
__global__ __launch_bounds__(256) void csr_build(const uint2* __restrict__ bkt,
                                                 const int* __restrict__ bbase,
                                                 int* __restrict__ rstart,
                                                 uint2* __restrict__ csr) {
    __shared__ int hcnt[256];
    __shared__ int sc[256];
    __shared__ int cur[256];
    const int t = threadIdx.x, b = blockIdx.x;
    const int beg = bbase[b], end = bbase[b + 1];
    hcnt[t] = 0;
    __syncthreads();
    for (int i = beg + t; i < end; i += 256)
        atomicAdd(&hcnt[bkt[i].x >> 17], 1);
    __syncthreads();
    int v = hcnt[t];
    sc[t] = v;
    __syncthreads();
    for (int off = 1; off < 256; off <<= 1) {
        int x = (t >= off) ? sc[t - off] : 0;
        __syncthreads();
        sc[t] += x;
        __syncthreads();
    }
    int excl = sc[t] - v;
    int row = b * 256 + t;
    if (row < N_NODES) rstart[row] = beg + excl;
    cur[t] = excl;
    __syncthreads();
    for (int i = beg + t; i < end; i += 256) {
        uint2 u = bkt[i];
        int lr = u.x >> 17;
        int off = atomicAdd(&cur[lr], 1);
        uint2 o;
        o.x = u.x & 0x1FFFFu;
        o.y = u.y;
        csr[beg + off] = o;
    }
}

// ---------------------------------------------------------------------------
// SpMM row-gather: one wave per node; lane owns 4 features (one dwordx2 per
// edge) -> whole 512 B pre-row in one VMEM instr per wave. Writes agg+bias.
// ---------------------------------------------------------------------------
__global__ __launch_bounds__(64) void spmm_kernel(const uint2* __restrict__ csr,
                                                  const int* __restrict__ row_start,
                                                  const ushort_t* __restrict__ pre,
                                                  const float* __restrict__ bias,
                                                  float* __restrict__ out) {
    __shared__ uint2 epairs[64];
    const int node = blockIdx.x;
    const int lane = threadIdx.x;
    const int beg = row_start[node], end = row_start[node + 1];
    float a0 = 0.f, a1 = 0.f, a2 = 0.f, a3 = 0.f;
    for (int base = beg; base < end; base += 64) {
        int cnt = min(end - base, 64);
        if (lane < cnt) epairs[lane] = csr[base + lane];
        __syncthreads();
        for (int e = 0; e < cnt; ++e) {
            uint2 p = epairs[e];
            float w = __uint_as_float(p.y);
            const uint_t* rowp = (const uint_t*)(pre + (size_t)p.x * D_OUT);
            uint2 g = *(const uint2*)(rowp + lane * 2);
            a0 = fmaf(w, bf2f(g.x & 0xFFFFu), a0);
            a1 = fmaf(w, bf2f(g.x >> 16), a1);
            a2 = fmaf(w, bf2f(g.y & 0xFFFFu), a2);
            a3 = fmaf(w, bf2f(g.y >> 16), a3);
        }
        __syncthreads();
    }
    const float* b4 = bias + lane * 4;
    f32x4 o;
    o[0] = a0 + b4[0]; o[1] = a1 + b4[1]; o[2] = a2 + b4[2]; o[3] = a3 + b4[3];
    *(f32x4*)(out + (size_t)node * D_OUT + lane * 4) = o;
}

// ---------------------------------------------------------------------------
// Column sum-of-squares, then in-place normalize + softplus
// ---------------------------------------------------------------------------
__global__ __launch_bounds__(256) void colsq_kernel(const float* __restrict__ out,
                                                    float* __restrict__ colsq) {
    const int f = threadIdx.x;
    float s = 0.f;
    for (int i = blockIdx.x; i < N_NODES; i += gridDim.x) {
        float v = out[(size_t)i * D_OUT + f];
        s = fmaf(v, v, s);
    }
    atomicAdd(&colsq[f], s);
}

__global__ __launch_bounds__(256) void finalize_kernel(float* __restrict__ out,
                                                       const float* __restrict__ colsq) {
    __shared__ float inv[256];
    const int t = threadIdx.x;
    float n = sqrtf(colsq[t]);
    inv[t] = 1.0f / fmaxf(n, 1e-12f);
    __syncthreads();
    const size_t total4 = (size_t)N_NODES * D_OUT / 4;
    for (size_t i = (size_t)blockIdx.x * 256 + t; i < total4; i += (size_t)gridDim.x * 256) {
        f32x4 v = ((const f32x4*)out)[i];
        int fbase = (int)((i * 4) & (D_OUT - 1));
        f32x4 o;
#pragma unroll
        for (int c = 0; c < 4; ++c) {
            float x = v[c] * inv[fbase + c];
            float tt = __expf(x);
            float y = __logf(1.0f + tt);
            o[c] = (x > 20.f) ? x : y;
        }
        ((f32x4*)out)[i] = o;
    }
}

// ---------------------------------------------------------------------------
extern "C" void kernel_launch(void* const* d_in, const int* in_sizes, int n_in,
                              void* d_out, int out_size, void* d_ws, size_t ws_size,
                              hipStream_t stream) {
    const float* x    = (const float*)d_in[0];
    const int*   erow = (const int*)d_in[1];
    const int*   ecol = (const int*)d_in[2];
    const float* eval = (const float*)d_in[3];
    const float* W    = (const float*)d_in[4];
    const float* b    = (const float*)d_in[5];
    float* out = (float*)d_out;
    char* ws = (char*)d_ws;

    // workspace layout (~77.5 MB). bkt (25.6 MB) overlays pre (51.2 MB):
    // bkt is dead after csr_build, which completes before gemm_xw launches.
    uint2*    bkt     = (uint2*)   (ws + 0);            // 25,600,000 B (temp)
    ushort_t* pre     = (ushort_t*)(ws + 0);            // 51,200,000 B
    uint2*    csr     = (uint2*)   (ws + 51200000);     // 25,600,000 B
    int*      rstart  = (int*)     (ws + 76800000);     //    400,004 B
    float*    colsq   = (float*)   (ws + 77200016);     //      1,024 B
    int*      bcnt    = (int*)     (ws + 77201040);     //      1,564 B
    int*      bbase   = (int*)     (ws + 77202608);     //      1,568 B
    int*      bcursor = (int*)     (ws + 77204176);     //      1,564 B
    ushort_t* Wt      = (ushort_t*)(ws + 77205760);     //    262,144 B

    (void)hipMemsetAsync(bcnt, 0, NBUK * sizeof(int), stream);
    (void)hipMemsetAsync(colsq, 0, D_OUT * sizeof(float), stream);

    bhist<<<782, 256, 0, stream>>>(erow, bcnt);
    bscan<<<1, 512, 0, stream>>>(bcnt, bbase, bcursor, rstart);
    bucket_scatter<<<782, 256, 0, stream>>>(erow, ecol, eval, bcursor, bkt);
    csr_build<<<NBUK, 256, 0, stream>>>(bkt, bbase, rstart, csr);
    cvt_w<<<512, 256, 0, stream>>>(W, Wt);
    gemm_xw<<<dim3(2, 782), 256, 0, stream>>>(x, Wt, pre);
    spmm_kernel<<<N_NODES, 64, 0, stream>>>(csr, rstart, pre, b, out);
    colsq_kernel<<<512, 256, 0, stream>>>(out, colsq);
    finalize_kernel<<<1024, 256, 0, stream>>>(out, colsq);
}